// Round 4
// baseline (586.203 us; speedup 1.0000x reference)
//
#include <hip/hip_runtime.h>

#define N_NODES 100000
#define N_EDGES 1600000
#define IN_DIM 64
#define H_DIM 128
#define OUT_DIM 64
#define BN_EPS 1e-5f
#define CAP 64        // padded-CSR capacity; deg ~ Poisson(16)
#define BIN_SHIFT 9
#define BIN_NODES 512
#define NB 256
#define NBIN_BLOCKS ((N_NODES + BIN_NODES - 1) / BIN_NODES)  // 196
#define MLP_GRID ((N_NODES + 127) / 128)                     // 782

// ---- workspace layout (float offsets, phase-disjoint overlays) ----
// [0    .. 3.2M)  : xb (bf16 x, 6.4M ushort)            live: prep..gather
// [3.2M .. 6.4M)  : binned (int2 1.6M) / comb (bf16 6.4M ushort)
//                   binned: bsplit..bfill; comb: gather..mlp
// [6.4M .. 12.8M) : srcl (int 6.4M)                     bfill..gather
// [16M  .. 16.1M) : cnt (int 100K)                      bfill..gather
// [19.2M..      ) : stats(768) + bhist(256) + boff(257) + bcur(256) + bar(2)
#define OFF_XB     0
#define OFF_BINNED 3200000
#define OFF_COMB   3200000
#define OFF_SRCL   6400000
#define OFF_CNT    16000000
#define OFF_STATS  19200000
#define S1SUM 0
#define S1SQ  128
#define S2SUM 256
#define S2SQ  320

#define DEV_ATOMIC_ADD(p, v) __hip_atomic_fetch_add((p), (v), __ATOMIC_RELAXED, __HIP_MEMORY_SCOPE_AGENT)

typedef __attribute__((ext_vector_type(8))) short short8;
typedef __attribute__((ext_vector_type(4))) float f32x4;

__device__ __forceinline__ unsigned short f2bf(float f) {
  union { float f; unsigned u; } v; v.f = f;
  unsigned r = v.u + 0x7FFFu + ((v.u >> 16) & 1u);
  return (unsigned short)(r >> 16);
}
__device__ __forceinline__ float bflo(unsigned v) { union { unsigned u; float f; } t; t.u = v << 16; return t.f; }
__device__ __forceinline__ float bfhi(unsigned v) { union { unsigned u; float f; } t; t.u = v & 0xFFFF0000u; return t.f; }

__device__ __forceinline__ void acc8(float* a, uint4 v) {
  a[0] += bflo(v.x); a[1] += bfhi(v.x); a[2] += bflo(v.y); a[3] += bfhi(v.y);
  a[4] += bflo(v.z); a[5] += bfhi(v.z); a[6] += bflo(v.w); a[7] += bfhi(v.w);
}
__device__ __forceinline__ uint4 pack8(const float* a) {
  uint4 o;
  o.x = (unsigned)f2bf(a[0]) | ((unsigned)f2bf(a[1]) << 16);
  o.y = (unsigned)f2bf(a[2]) | ((unsigned)f2bf(a[3]) << 16);
  o.z = (unsigned)f2bf(a[4]) | ((unsigned)f2bf(a[5]) << 16);
  o.w = (unsigned)f2bf(a[6]) | ((unsigned)f2bf(a[7]) << 16);
  return o;
}

// ---- prep: x fp32->bf16 conversion + bin histogram (fused independent streams) ----
__global__ __launch_bounds__(256) void k_prep(const float* __restrict__ x,
                                              unsigned short* __restrict__ xb,
                                              const int* __restrict__ ei,
                                              int* __restrict__ bhist) {
  __shared__ int h[NB];
  const int tid = threadIdx.x;
  h[tid] = 0;
  #pragma unroll
  for (int j = 0; j < 8; ++j) {
    int i = blockIdx.x * 2048 + j * 256 + tid;
    if (i < N_NODES * IN_DIM / 4) {
      float4 v = ((const float4*)x)[i];
      ushort4 o;
      o.x = f2bf(v.x); o.y = f2bf(v.y); o.z = f2bf(v.z); o.w = f2bf(v.w);
      *(ushort4*)(xb + i * 4) = o;
    }
  }
  __syncthreads();
  #pragma unroll
  for (int j = 0; j < 8; ++j) {
    int e = blockIdx.x * 2048 + j * 256 + tid;
    if (e < N_EDGES) atomicAdd(&h[ei[N_EDGES + e] >> BIN_SHIFT], 1);
  }
  __syncthreads();
  if (h[tid]) DEV_ATOMIC_ADD(&bhist[tid], h[tid]);
}

// ---- 256-wide exclusive scan ----
__global__ __launch_bounds__(256) void k_scan256(const int* __restrict__ bhist,
                                                 int* __restrict__ boff,
                                                 int* __restrict__ bcur) {
  __shared__ int s[NB];
  const int tid = threadIdx.x;
  int v = bhist[tid];
  s[tid] = v;
  __syncthreads();
  for (int d = 1; d < NB; d <<= 1) {
    int t = (tid >= d) ? s[tid - d] : 0;
    __syncthreads();
    s[tid] += t;
    __syncthreads();
  }
  int incl = s[tid];
  boff[tid] = incl - v;
  if (tid == NB - 1) boff[NB] = incl;
  bcur[tid] = incl - v;
}

// ---- multisplit with LDS counting-sort: coalesced bin-run writes ----
__global__ __launch_bounds__(256) void k_bsplit(const int* __restrict__ ei,
                                                int* __restrict__ bcur,
                                                int2* __restrict__ binned) {
  __shared__ int lcnt[NB];
  __shared__ int lofs[NB];
  __shared__ int lbase[NB];
  __shared__ int sc[NB];
  __shared__ int2 staged[2048];   // 16 KB
  const int tid = threadIdx.x;
  lcnt[tid] = 0;
  __syncthreads();
  int src[8], dst[8], rk[8];
  #pragma unroll
  for (int j = 0; j < 8; ++j) {
    int e = blockIdx.x * 2048 + j * 256 + tid;
    if (e < N_EDGES) {
      src[j] = ei[e];
      dst[j] = ei[N_EDGES + e];
      rk[j] = atomicAdd(&lcnt[dst[j] >> BIN_SHIFT], 1);
    } else {
      src[j] = -1;
    }
  }
  __syncthreads();
  int v = lcnt[tid];
  sc[tid] = v;
  __syncthreads();
  for (int d = 1; d < NB; d <<= 1) {
    int t = (tid >= d) ? sc[tid - d] : 0;
    __syncthreads();
    sc[tid] += t;
    __syncthreads();
  }
  lofs[tid] = sc[tid] - v;
  if (v > 0) lbase[tid] = DEV_ATOMIC_ADD(&bcur[tid], v);
  __syncthreads();
  #pragma unroll
  for (int j = 0; j < 8; ++j) {
    if (src[j] >= 0) {
      int b = dst[j] >> BIN_SHIFT;
      staged[lofs[b] + rk[j]] = make_int2(src[j], dst[j]);
    }
  }
  int nv = sc[NB - 1];
  __syncthreads();
  for (int i = tid; i < nv; i += 256) {
    int2 e = staged[i];
    int b = e.y >> BIN_SHIFT;
    binned[lbase[b] + (i - lofs[b])] = e;
  }
}

// ---- per-bin CSR fill (XCD-local scatter, LDS tickets) ----
__global__ __launch_bounds__(512) void k_bfill(const int* __restrict__ boff,
                                               const int2* __restrict__ binned,
                                               int* __restrict__ cnt,
                                               int* __restrict__ srcl) {
  __shared__ int lcnt[BIN_NODES];
  const int tid = threadIdx.x;
  for (int i = tid; i < BIN_NODES; i += 512) lcnt[i] = 0;
  __syncthreads();
  const int b = blockIdx.x;
  const int s = boff[b], e = boff[b + 1];
  const int base = b * BIN_NODES;
  for (int i = s + tid; i < e; i += 512) {
    int2 ed = binned[i];
    int pos = atomicAdd(&lcnt[ed.y - base], 1);
    if (pos < CAP) srcl[ed.y * CAP + pos] = ed.x;
  }
  __syncthreads();
  for (int i = tid; i < BIN_NODES; i += 512) {
    int node = base + i;
    if (node < N_NODES) cnt[node] = lcnt[i];
  }
}

// ---- gather: comb(bf16) = (1+eps)*x + sum(neighbors), LDS-free deep-MLP streaming ----
__global__ __launch_bounds__(256, 5) void k_gather(const unsigned short* __restrict__ xb,
                                                   const float* __restrict__ eps,
                                                   const int* __restrict__ cnt,
                                                   const int* __restrict__ srcl,
                                                   unsigned short* __restrict__ comb) {
  const int t = blockIdx.x * 256 + threadIdx.x;
  const int node = t >> 3;
  const int sub = t & 7;
  if (node >= N_NODES) return;

  float a[8];
  {
    uint4 sv = *(const uint4*)(xb + node * 64 + sub * 8);
    float e1 = 1.0f + eps[0];
    a[0] = bflo(sv.x) * e1; a[1] = bfhi(sv.x) * e1;
    a[2] = bflo(sv.y) * e1; a[3] = bfhi(sv.y) * e1;
    a[4] = bflo(sv.z) * e1; a[5] = bfhi(sv.z) * e1;
    a[6] = bflo(sv.w) * e1; a[7] = bfhi(sv.w) * e1;
  }
  int deg = cnt[node];
  if (deg > CAP) deg = CAP;
  const int* sl = srcl + node * CAP;

  uint4 n0 = *(const uint4*)sl;
  uint4 n1 = *(const uint4*)(sl + 4);
  int j = 0;
  while (j + 8 <= deg) {
    uint4 i0 = n0, i1 = n1;
    uint4 r0 = *(const uint4*)(xb + (size_t)i0.x * 64 + sub * 8);
    uint4 r1 = *(const uint4*)(xb + (size_t)i0.y * 64 + sub * 8);
    uint4 r2 = *(const uint4*)(xb + (size_t)i0.z * 64 + sub * 8);
    uint4 r3 = *(const uint4*)(xb + (size_t)i0.w * 64 + sub * 8);
    uint4 r4 = *(const uint4*)(xb + (size_t)i1.x * 64 + sub * 8);
    uint4 r5 = *(const uint4*)(xb + (size_t)i1.y * 64 + sub * 8);
    uint4 r6 = *(const uint4*)(xb + (size_t)i1.z * 64 + sub * 8);
    uint4 r7 = *(const uint4*)(xb + (size_t)i1.w * 64 + sub * 8);
    j += 8;
    n0 = *(const uint4*)(sl + j);
    n1 = *(const uint4*)(sl + j + 4);
    acc8(a, r0); acc8(a, r1); acc8(a, r2); acc8(a, r3);
    acc8(a, r4); acc8(a, r5); acc8(a, r6); acc8(a, r7);
  }
  if (j + 4 <= deg) {
    uint4 i0 = *(const uint4*)(sl + j);
    uint4 r0 = *(const uint4*)(xb + (size_t)i0.x * 64 + sub * 8);
    uint4 r1 = *(const uint4*)(xb + (size_t)i0.y * 64 + sub * 8);
    uint4 r2 = *(const uint4*)(xb + (size_t)i0.z * 64 + sub * 8);
    uint4 r3 = *(const uint4*)(xb + (size_t)i0.w * 64 + sub * 8);
    acc8(a, r0); acc8(a, r1); acc8(a, r2); acc8(a, r3);
    j += 4;
  }
  if (j + 2 <= deg) {
    int2 i2 = *(const int2*)(sl + j);
    uint4 r0 = *(const uint4*)(xb + (size_t)i2.x * 64 + sub * 8);
    uint4 r1 = *(const uint4*)(xb + (size_t)i2.y * 64 + sub * 8);
    acc8(a, r0); acc8(a, r1);
    j += 2;
  }
  if (j < deg) {
    int s0 = sl[j];
    uint4 r0 = *(const uint4*)(xb + (size_t)s0 * 64 + sub * 8);
    acc8(a, r0);
  }
  *(uint4*)(comb + node * 64 + sub * 8) = pack8(a);
}

// ---- mlp: fused gemm1 + BN1 + relu + gemm2 + BN2 + out, persistent with grid barriers ----
// Co-residency guaranteed: 782 blocks, 4 blocks/CU (LDS 37.9KB, launch_bounds(256,4)) -> 1024 slots.
// Phase1 LDS {As 17KB + Ws1 17KB} overlaid by phase2 H[128][136] (34.8KB).
#define KP 68     // As/Ws1 row stride (shorts): 136 B, 16B-aligned, 2-way banks (free)
#define HP 136    // H row stride (shorts): 272 B, 16B-aligned, 2-way banks (free)

__device__ __forceinline__ void gridbar(int* bar, int nblk) {
  __syncthreads();
  if (threadIdx.x == 0) {
    __hip_atomic_fetch_add(bar, 1, __ATOMIC_ACQ_REL, __HIP_MEMORY_SCOPE_AGENT);
    while (__hip_atomic_load(bar, __ATOMIC_ACQUIRE, __HIP_MEMORY_SCOPE_AGENT) < nblk) {
      __builtin_amdgcn_s_sleep(4);
    }
  }
  __syncthreads();
}

__global__ __launch_bounds__(256, 4) void k_mlp(const unsigned short* __restrict__ comb,
                                                const float* __restrict__ W1,
                                                const float* __restrict__ b1,
                                                const float* __restrict__ g1,
                                                const float* __restrict__ be1,
                                                const float* __restrict__ W2,
                                                const float* __restrict__ b2,
                                                const float* __restrict__ g2,
                                                const float* __restrict__ be2,
                                                float* __restrict__ stats,
                                                int* __restrict__ bar,
                                                float* __restrict__ out) {
  __shared__ unsigned short smem[17408];   // 34816 B: phase1 As+Ws1, phase2 H
  __shared__ float red[4][128];            // 2 KB
  __shared__ float scl[128], shl[128];     // 1 KB
  unsigned short* As  = smem;              // 128 x KP
  unsigned short* Ws1 = smem + 128 * KP;   // 128 x KP
  unsigned short* H   = smem;              // 128 x HP (overlay)
  const int tid = threadIdx.x;
  const int wv = tid >> 6, lane = tid & 63;
  const int quad = lane >> 4, ln = lane & 15;
  const int rowBase = blockIdx.x * 128;
  const int nblk = gridDim.x;

  // ---- phase 1: gemm1 ----
  #pragma unroll
  for (int it = 0; it < 8; ++it) {
    int idx = it * 256 + tid;
    int k = idx >> 5, n4 = idx & 31;
    float4 wv1 = *(const float4*)(W1 + k * 128 + n4 * 4);
    Ws1[(n4 * 4 + 0) * KP + k] = f2bf(wv1.x);
    Ws1[(n4 * 4 + 1) * KP + k] = f2bf(wv1.y);
    Ws1[(n4 * 4 + 2) * KP + k] = f2bf(wv1.z);
    Ws1[(n4 * 4 + 3) * KP + k] = f2bf(wv1.w);
  }
  #pragma unroll
  for (int it = 0; it < 4; ++it) {
    int idx = it * 256 + tid;           // 1024 uint4 = 128 rows x 8 chunks
    int row = idx >> 3, ch = idx & 7;
    int g = rowBase * 8 + idx;
    uint4 u = (g < N_NODES * 8) ? ((const uint4*)comb)[g] : make_uint4(0, 0, 0, 0);
    *(uint4*)&As[row * KP + ch * 8] = u;
  }
  __syncthreads();

  f32x4 acc[2][8];
  #pragma unroll
  for (int mt = 0; mt < 2; ++mt)
    #pragma unroll
    for (int nt = 0; nt < 8; ++nt) acc[mt][nt] = (f32x4)0.0f;
  const int rw = wv * 32;
  #pragma unroll
  for (int kb = 0; kb < 2; ++kb) {
    short8 a0 = *(short8*)&As[(rw + ln) * KP + kb * 32 + quad * 8];
    short8 a1 = *(short8*)&As[(rw + 16 + ln) * KP + kb * 32 + quad * 8];
    #pragma unroll
    for (int nt = 0; nt < 8; ++nt) {
      short8 b = *(short8*)&Ws1[(nt * 16 + ln) * KP + kb * 32 + quad * 8];
      acc[0][nt] = __builtin_amdgcn_mfma_f32_16x16x32_bf16(a0, b, acc[0][nt], 0, 0, 0);
      acc[1][nt] = __builtin_amdgcn_mfma_f32_16x16x32_bf16(a1, b, acc[1][nt], 0, 0, 0);
    }
  }
  __syncthreads();   // all As/Ws1 reads done; smem can become H

  {
    float bias[8], s[8], q[8];
    #pragma unroll
    for (int nt = 0; nt < 8; ++nt) { bias[nt] = b1[nt * 16 + ln]; s[nt] = 0.f; q[nt] = 0.f; }
    #pragma unroll
    for (int mt = 0; mt < 2; ++mt) {
      #pragma unroll
      for (int i = 0; i < 4; ++i) {
        int lRow = rw + mt * 16 + quad * 4 + i;
        int gRow = rowBase + lRow;
        bool ok = gRow < N_NODES;
        #pragma unroll
        for (int nt = 0; nt < 8; ++nt) {
          float v = acc[mt][nt][i] + bias[nt];
          H[lRow * HP + nt * 16 + ln] = f2bf(v);
          if (ok) { s[nt] += v; q[nt] += v * v; }
        }
      }
    }
    #pragma unroll
    for (int nt = 0; nt < 8; ++nt) {
      s[nt] += __shfl_xor(s[nt], 16); s[nt] += __shfl_xor(s[nt], 32);
      q[nt] += __shfl_xor(q[nt], 16); q[nt] += __shfl_xor(q[nt], 32);
    }
    if (lane < 16) {
      #pragma unroll
      for (int nt = 0; nt < 8; ++nt) red[wv][nt * 16 + ln] = s[nt];
    }
    __syncthreads();
    if (tid < 128) DEV_ATOMIC_ADD(&stats[S1SUM + tid],
                                  red[0][tid] + red[1][tid] + red[2][tid] + red[3][tid]);
    __syncthreads();
    if (lane < 16) {
      #pragma unroll
      for (int nt = 0; nt < 8; ++nt) red[wv][nt * 16 + ln] = q[nt];
    }
    __syncthreads();
    if (tid < 128) DEV_ATOMIC_ADD(&stats[S1SQ + tid],
                                  red[0][tid] + red[1][tid] + red[2][tid] + red[3][tid]);
  }

  gridbar(&bar[0], nblk);   // BN1 join

  if (tid < 128) {
    float su = __hip_atomic_load(&stats[S1SUM + tid], __ATOMIC_ACQUIRE, __HIP_MEMORY_SCOPE_AGENT);
    float sq = __hip_atomic_load(&stats[S1SQ + tid], __ATOMIC_ACQUIRE, __HIP_MEMORY_SCOPE_AGENT);
    float mean = su * (1.0f / N_NODES);
    float var = sq * (1.0f / N_NODES) - mean * mean;
    var = fmaxf(var, 0.0f);
    float sc = g1[tid] * rsqrtf(var + BN_EPS);
    scl[tid] = sc;
    shl[tid] = be1[tid] - mean * sc;
  }
  __syncthreads();

  // BN1 + relu in place on H (bf16 -> f32 -> bf16, same rounding as split kernels)
  #pragma unroll
  for (int it = 0; it < 8; ++it) {
    int idx = it * 256 + tid;           // 2048 = 128 rows x 16 chunks
    int row = idx >> 4, ch = idx & 15;
    uint4* p = (uint4*)&H[row * HP + ch * 8];
    uint4 u = *p;
    int kb = ch * 8;
    float f0 = fmaxf(bflo(u.x) * scl[kb + 0] + shl[kb + 0], 0.f);
    float f1 = fmaxf(bfhi(u.x) * scl[kb + 1] + shl[kb + 1], 0.f);
    float f2 = fmaxf(bflo(u.y) * scl[kb + 2] + shl[kb + 2], 0.f);
    float f3 = fmaxf(bfhi(u.y) * scl[kb + 3] + shl[kb + 3], 0.f);
    float f4 = fmaxf(bflo(u.z) * scl[kb + 4] + shl[kb + 4], 0.f);
    float f5 = fmaxf(bfhi(u.z) * scl[kb + 5] + shl[kb + 5], 0.f);
    float f6 = fmaxf(bflo(u.w) * scl[kb + 6] + shl[kb + 6], 0.f);
    float f7 = fmaxf(bfhi(u.w) * scl[kb + 7] + shl[kb + 7], 0.f);
    uint4 o;
    o.x = (unsigned)f2bf(f0) | ((unsigned)f2bf(f1) << 16);
    o.y = (unsigned)f2bf(f2) | ((unsigned)f2bf(f3) << 16);
    o.z = (unsigned)f2bf(f4) | ((unsigned)f2bf(f5) << 16);
    o.w = (unsigned)f2bf(f6) | ((unsigned)f2bf(f7) << 16);
    *p = o;
  }
  __syncthreads();

  // ---- phase 2: gemm2 (W2 B-frags rebuilt in regs per kc half; L2-hot) ----
  f32x4 acc2[2][4];
  #pragma unroll
  for (int mt = 0; mt < 2; ++mt)
    #pragma unroll
    for (int nt = 0; nt < 4; ++nt) acc2[mt][nt] = (f32x4)0.0f;

  #pragma unroll
  for (int kc = 0; kc < 2; ++kc) {
    short8 wf[4][2];
    #pragma unroll
    for (int nt = 0; nt < 4; ++nt) {
      #pragma unroll
      for (int kb = 0; kb < 2; ++kb) {
        short8 f;
        #pragma unroll
        for (int j = 0; j < 8; ++j) {
          int k = kc * 64 + kb * 32 + quad * 8 + j;
          f[j] = (short)f2bf(W2[k * 64 + nt * 16 + ln]);
        }
        wf[nt][kb] = f;
      }
    }
    #pragma unroll
    for (int kb = 0; kb < 2; ++kb) {
      short8 a0 = *(short8*)&H[(rw + ln) * HP + kc * 64 + kb * 32 + quad * 8];
      short8 a1 = *(short8*)&H[(rw + 16 + ln) * HP + kc * 64 + kb * 32 + quad * 8];
      #pragma unroll
      for (int nt = 0; nt < 4; ++nt) {
        acc2[0][nt] = __builtin_amdgcn_mfma_f32_16x16x32_bf16(a0, wf[nt][kb], acc2[0][nt], 0, 0, 0);
        acc2[1][nt] = __builtin_amdgcn_mfma_f32_16x16x32_bf16(a1, wf[nt][kb], acc2[1][nt], 0, 0, 0);
      }
    }
  }

  {
    float bias[4], s[4], q[4];
    #pragma unroll
    for (int nt = 0; nt < 4; ++nt) { bias[nt] = b2[nt * 16 + ln]; s[nt] = 0.f; q[nt] = 0.f; }
    #pragma unroll
    for (int mt = 0; mt < 2; ++mt) {
      #pragma unroll
      for (int i = 0; i < 4; ++i) {
        int gRow = rowBase + rw + mt * 16 + quad * 4 + i;
        bool ok = gRow < N_NODES;
        #pragma unroll
        for (int nt = 0; nt < 4; ++nt) {
          float v = acc2[mt][nt][i] + bias[nt];
          if (ok) { s[nt] += v; q[nt] += v * v; }
          // keep h2 bf16-rounded value for the out phase (reuse acc2 storage)
          acc2[mt][nt][i] = bflo((unsigned)f2bf(v));
        }
      }
    }
    #pragma unroll
    for (int nt = 0; nt < 4; ++nt) {
      s[nt] += __shfl_xor(s[nt], 16); s[nt] += __shfl_xor(s[nt], 32);
      q[nt] += __shfl_xor(q[nt], 16); q[nt] += __shfl_xor(q[nt], 32);
    }
    if (lane < 16) {
      #pragma unroll
      for (int nt = 0; nt < 4; ++nt) red[wv][nt * 16 + ln] = s[nt];
    }
    __syncthreads();
    if (tid < 64) DEV_ATOMIC_ADD(&stats[S2SUM + tid],
                                 red[0][tid] + red[1][tid] + red[2][tid] + red[3][tid]);
    __syncthreads();
    if (lane < 16) {
      #pragma unroll
      for (int nt = 0; nt < 4; ++nt) red[wv][nt * 16 + ln] = q[nt];
    }
    __syncthreads();
    if (tid < 64) DEV_ATOMIC_ADD(&stats[S2SQ + tid],
                                 red[0][tid] + red[1][tid] + red[2][tid] + red[3][tid]);
  }

  gridbar(&bar[1], nblk);   // BN2 join

  float sc2[4], sh2[4];
  #pragma unroll
  for (int nt = 0; nt < 4; ++nt) {
    int c = nt * 16 + ln;
    float su = __hip_atomic_load(&stats[S2SUM + c], __ATOMIC_ACQUIRE, __HIP_MEMORY_SCOPE_AGENT);
    float sq = __hip_atomic_load(&stats[S2SQ + c], __ATOMIC_ACQUIRE, __HIP_MEMORY_SCOPE_AGENT);
    float mean = su * (1.0f / N_NODES);
    float var = sq * (1.0f / N_NODES) - mean * mean;
    var = fmaxf(var, 0.0f);
    float sc = g2[c] * rsqrtf(var + BN_EPS);
    sc2[nt] = sc;
    sh2[nt] = be2[c] - mean * sc;
  }
  #pragma unroll
  for (int mt = 0; mt < 2; ++mt) {
    #pragma unroll
    for (int i = 0; i < 4; ++i) {
      int gRow = rowBase + rw + mt * 16 + quad * 4 + i;
      if (gRow < N_NODES) {
        #pragma unroll
        for (int nt = 0; nt < 4; ++nt) {
          out[gRow * 64 + nt * 16 + ln] = acc2[mt][nt][i] * sc2[nt] + sh2[nt];
        }
      }
    }
  }
}

extern "C" void kernel_launch(void* const* d_in, const int* in_sizes, int n_in,
                              void* d_out, int out_size, void* d_ws, size_t ws_size,
                              hipStream_t stream) {
  const float* x   = (const float*)d_in[0];
  const int*   ei  = (const int*)d_in[1];
  const float* eps = (const float*)d_in[2];
  const float* W1  = (const float*)d_in[3];
  const float* b1  = (const float*)d_in[4];
  const float* g1  = (const float*)d_in[5];
  const float* be1 = (const float*)d_in[6];
  const float* W2  = (const float*)d_in[7];
  const float* b2  = (const float*)d_in[8];
  const float* g2  = (const float*)d_in[9];
  const float* be2 = (const float*)d_in[10];

  float* ws = (float*)d_ws;
  unsigned short* xb     = (unsigned short*)(ws + OFF_XB);
  int2*           binned = (int2*)(ws + OFF_BINNED);
  unsigned short* comb   = (unsigned short*)(ws + OFF_COMB);  // alias binned (dead after bfill)
  int*            srcl   = (int*)(ws + OFF_SRCL);
  int*            cnt    = (int*)(ws + OFF_CNT);
  float*          stats  = ws + OFF_STATS;
  int*            bhist  = (int*)(stats + 768);
  int*            boff   = (int*)(stats + 1024);  // 257 ints
  int*            bcur   = (int*)(stats + 1288);  // 256 ints
  int*            bar    = (int*)(stats + 1544);  // 2 ints
  float*          out    = (float*)d_out;

  // one memset covers stats(768) + bhist(256) + (boff/bcur, rewritten by scan) + bar(2)
  hipMemsetAsync(stats, 0, 1552 * sizeof(float), stream);

  const int edgeGrid = (N_EDGES + 2047) / 2048;            // 782
  const int gatherGrid = (N_NODES * 8 + 255) / 256;        // 3125
  k_prep<<<edgeGrid, 256, 0, stream>>>(x, xb, ei, bhist);
  k_scan256<<<1, NB, 0, stream>>>(bhist, boff, bcur);
  k_bsplit<<<edgeGrid, 256, 0, stream>>>(ei, bcur, binned);
  k_bfill<<<NBIN_BLOCKS, 512, 0, stream>>>(boff, binned, cnt, srcl);
  k_gather<<<gatherGrid, 256, 0, stream>>>(xb, eps, cnt, srcl, comb);
  k_mlp<<<MLP_GRID, 256, 0, stream>>>(comb, W1, b1, g1, be1, W2, b2, g2, be2,
                                      stats, bar, out);
}

// Round 6
// 239.177 us; speedup vs baseline: 2.4509x; 2.4509x over previous
//
#include <hip/hip_runtime.h>

#define N_NODES 100000
#define N_EDGES 1600000
#define IN_DIM 64
#define H_DIM 128
#define OUT_DIM 64
#define BN_EPS 1e-5f
#define CAP 64        // padded-CSR capacity; deg ~ Poisson(16)
#define BIN_SHIFT 9
#define BIN_NODES 512
#define NB 256
#define BINCAP 10240  // per-bin edge capacity: mean 8192 (=512*16), sigma~90 -> +22.6σ
#define NBIN_BLOCKS ((N_NODES + BIN_NODES - 1) / BIN_NODES)  // 196

// ---- workspace layout (float offsets, no aliasing; int2 = 2 floats) ----
// [0    .. 3.2M)   : xb (bf16 x, 6.4M ushort)
// [3.2M .. 9.6M)   : srcl (int 6.4M = 100K x CAP)
// [9.6M .. 14.9M)  : binned (int2, 256 bins x BINCAP = 5.24M int2)
// [15.0M.. 18.2M)  : comb (bf16, 6.4M ushort)
// [18.2M.. 24.6M)  : h1 (bf16, 12.8M ushort)
// [24.6M.. 27.8M)  : h2 (bf16, 6.4M ushort)
// [27.8M.. 27.9M)  : cnt (int 100K)
// [28.0M..       ) : stats(768) + bcnt(256)
#define OFF_XB     0
#define OFF_SRCL   3200000
#define OFF_BINNED 9600000
#define OFF_COMB   15000000
#define OFF_H1     18200000
#define OFF_H2     24600000
#define OFF_CNT    27800000
#define OFF_STATS  28000000
#define S1SUM 0
#define S1SQ  128
#define S2SUM 256
#define S2SQ  320

#define DEV_ATOMIC_ADD(p, v) __hip_atomic_fetch_add((p), (v), __ATOMIC_RELAXED, __HIP_MEMORY_SCOPE_AGENT)

typedef __attribute__((ext_vector_type(8))) short short8;
typedef __attribute__((ext_vector_type(4))) float f32x4;

__device__ __forceinline__ unsigned short f2bf(float f) {
  union { float f; unsigned u; } v; v.f = f;
  unsigned r = v.u + 0x7FFFu + ((v.u >> 16) & 1u);
  return (unsigned short)(r >> 16);
}
__device__ __forceinline__ float bflo(unsigned v) { union { unsigned u; float f; } t; t.u = v << 16; return t.f; }
__device__ __forceinline__ float bfhi(unsigned v) { union { unsigned u; float f; } t; t.u = v & 0xFFFF0000u; return t.f; }

__device__ __forceinline__ void acc8(float* a, uint4 v) {
  a[0] += bflo(v.x); a[1] += bfhi(v.x); a[2] += bflo(v.y); a[3] += bfhi(v.y);
  a[4] += bflo(v.z); a[5] += bfhi(v.z); a[6] += bflo(v.w); a[7] += bfhi(v.w);
}
__device__ __forceinline__ uint4 pack8(const float* a) {
  uint4 o;
  o.x = (unsigned)f2bf(a[0]) | ((unsigned)f2bf(a[1]) << 16);
  o.y = (unsigned)f2bf(a[2]) | ((unsigned)f2bf(a[3]) << 16);
  o.z = (unsigned)f2bf(a[4]) | ((unsigned)f2bf(a[5]) << 16);
  o.w = (unsigned)f2bf(a[6]) | ((unsigned)f2bf(a[7]) << 16);
  return o;
}

// ---- bsplit: x fp32->bf16 conversion (stream 1) + single-pass edge multisplit
//      into capacity-padded bins (stream 2). No histogram, no scan kernel. ----
__global__ __launch_bounds__(256) void k_bsplit(const float* __restrict__ x,
                                                unsigned short* __restrict__ xb,
                                                const int* __restrict__ ei,
                                                int* __restrict__ bcnt,
                                                int2* __restrict__ binned) {
  __shared__ int lcnt[NB];
  __shared__ int lbase[NB];
  const int tid = threadIdx.x;
  lcnt[tid] = 0;
  // stream 1: convert 2048 float4 per block
  #pragma unroll
  for (int j = 0; j < 8; ++j) {
    int i = blockIdx.x * 2048 + j * 256 + tid;
    if (i < N_NODES * IN_DIM / 4) {
      float4 v = ((const float4*)x)[i];
      ushort4 o;
      o.x = f2bf(v.x); o.y = f2bf(v.y); o.z = f2bf(v.z); o.w = f2bf(v.w);
      *(ushort4*)(xb + i * 4) = o;
    }
  }
  __syncthreads();
  // stream 2: 2048 edges per block, LDS rank + global bin reservation
  int src[8], dst[8], rk[8];
  #pragma unroll
  for (int j = 0; j < 8; ++j) {
    int e = blockIdx.x * 2048 + j * 256 + tid;
    if (e < N_EDGES) {
      src[j] = ei[e];
      dst[j] = ei[N_EDGES + e];
      rk[j] = atomicAdd(&lcnt[dst[j] >> BIN_SHIFT], 1);
    } else {
      src[j] = -1;
    }
  }
  __syncthreads();
  if (lcnt[tid] > 0) lbase[tid] = DEV_ATOMIC_ADD(&bcnt[tid], lcnt[tid]);
  __syncthreads();
  #pragma unroll
  for (int j = 0; j < 8; ++j) {
    if (src[j] >= 0) {
      int b = dst[j] >> BIN_SHIFT;
      int pos = lbase[b] + rk[j];
      if (pos < BINCAP) binned[b * BINCAP + pos] = make_int2(src[j], dst[j]);
    }
  }
}

// ---- per-bin CSR fill (XCD-local scatter, LDS tickets) ----
__global__ __launch_bounds__(512) void k_bfill(const int* __restrict__ bcnt,
                                               const int2* __restrict__ binned,
                                               int* __restrict__ cnt,
                                               int* __restrict__ srcl) {
  __shared__ int lcnt[BIN_NODES];
  const int tid = threadIdx.x;
  for (int i = tid; i < BIN_NODES; i += 512) lcnt[i] = 0;
  __syncthreads();
  const int b = blockIdx.x;
  int n = bcnt[b];
  if (n > BINCAP) n = BINCAP;
  const int2* run = binned + b * BINCAP;
  const int base = b * BIN_NODES;
  for (int i = tid; i < n; i += 512) {
    int2 ed = run[i];
    int pos = atomicAdd(&lcnt[ed.y - base], 1);
    if (pos < CAP) srcl[ed.y * CAP + pos] = ed.x;
  }
  __syncthreads();
  for (int i = tid; i < BIN_NODES; i += 512) {
    int node = base + i;
    if (node < N_NODES) cnt[node] = lcnt[i];
  }
}

// ---- gather: comb(bf16) = (1+eps)*x + sum(neighbors), LDS-free deep-MLP streaming ----
__global__ __launch_bounds__(256, 5) void k_gather(const unsigned short* __restrict__ xb,
                                                   const float* __restrict__ eps,
                                                   const int* __restrict__ cnt,
                                                   const int* __restrict__ srcl,
                                                   unsigned short* __restrict__ comb) {
  const int t = blockIdx.x * 256 + threadIdx.x;
  const int node = t >> 3;
  const int sub = t & 7;
  if (node >= N_NODES) return;

  float a[8];
  {
    uint4 sv = *(const uint4*)(xb + node * 64 + sub * 8);
    float e1 = 1.0f + eps[0];
    a[0] = bflo(sv.x) * e1; a[1] = bfhi(sv.x) * e1;
    a[2] = bflo(sv.y) * e1; a[3] = bfhi(sv.y) * e1;
    a[4] = bflo(sv.z) * e1; a[5] = bfhi(sv.z) * e1;
    a[6] = bflo(sv.w) * e1; a[7] = bfhi(sv.w) * e1;
  }
  int deg = cnt[node];
  if (deg > CAP) deg = CAP;
  const int* sl = srcl + node * CAP;

  uint4 n0 = *(const uint4*)sl;
  uint4 n1 = *(const uint4*)(sl + 4);
  int j = 0;
  while (j + 8 <= deg) {
    uint4 i0 = n0, i1 = n1;
    uint4 r0 = *(const uint4*)(xb + (size_t)i0.x * 64 + sub * 8);
    uint4 r1 = *(const uint4*)(xb + (size_t)i0.y * 64 + sub * 8);
    uint4 r2 = *(const uint4*)(xb + (size_t)i0.z * 64 + sub * 8);
    uint4 r3 = *(const uint4*)(xb + (size_t)i0.w * 64 + sub * 8);
    uint4 r4 = *(const uint4*)(xb + (size_t)i1.x * 64 + sub * 8);
    uint4 r5 = *(const uint4*)(xb + (size_t)i1.y * 64 + sub * 8);
    uint4 r6 = *(const uint4*)(xb + (size_t)i1.z * 64 + sub * 8);
    uint4 r7 = *(const uint4*)(xb + (size_t)i1.w * 64 + sub * 8);
    j += 8;
    n0 = *(const uint4*)(sl + j);
    n1 = *(const uint4*)(sl + j + 4);
    acc8(a, r0); acc8(a, r1); acc8(a, r2); acc8(a, r3);
    acc8(a, r4); acc8(a, r5); acc8(a, r6); acc8(a, r7);
  }
  if (j + 4 <= deg) {
    uint4 i0 = *(const uint4*)(sl + j);
    uint4 r0 = *(const uint4*)(xb + (size_t)i0.x * 64 + sub * 8);
    uint4 r1 = *(const uint4*)(xb + (size_t)i0.y * 64 + sub * 8);
    uint4 r2 = *(const uint4*)(xb + (size_t)i0.z * 64 + sub * 8);
    uint4 r3 = *(const uint4*)(xb + (size_t)i0.w * 64 + sub * 8);
    acc8(a, r0); acc8(a, r1); acc8(a, r2); acc8(a, r3);
    j += 4;
  }
  if (j + 2 <= deg) {
    int2 i2 = *(const int2*)(sl + j);
    uint4 r0 = *(const uint4*)(xb + (size_t)i2.x * 64 + sub * 8);
    uint4 r1 = *(const uint4*)(xb + (size_t)i2.y * 64 + sub * 8);
    acc8(a, r0); acc8(a, r1);
    j += 2;
  }
  if (j < deg) {
    int s0 = sl[j];
    uint4 r0 = *(const uint4*)(xb + (size_t)s0 * 64 + sub * 8);
    acc8(a, r0);
  }
  *(uint4*)(comb + node * 64 + sub * 8) = pack8(a);
}

// ---- gemm1: h1(bf16) = comb @ W1 + b1 (bf16 MFMA), fused BN1 raw stats ----
#define APAD 72
__global__ __launch_bounds__(256) void k_gemm1(const unsigned short* __restrict__ comb,
                                               const float* __restrict__ W1,
                                               const float* __restrict__ b1,
                                               unsigned short* __restrict__ h1,
                                               float* __restrict__ stats) {
  __shared__ unsigned short As[128 * APAD];   // 18 KB
  __shared__ unsigned short Ws[128 * APAD];   // 18 KB
  __shared__ float red[4][128];
  const int tid = threadIdx.x;
  const int wv = tid >> 6, lane = tid & 63;
  const int quad = lane >> 4, ln = lane & 15;
  const int rowBase = blockIdx.x * 128;

  // stage Wt[n][k] bf16 from W1 fp32 [64][128]
  #pragma unroll
  for (int it = 0; it < 8; ++it) {
    int idx = it * 256 + tid;
    int k = idx >> 5, n4 = idx & 31;
    float4 wv1 = *(const float4*)(W1 + k * 128 + n4 * 4);
    Ws[(n4 * 4 + 0) * APAD + k] = f2bf(wv1.x);
    Ws[(n4 * 4 + 1) * APAD + k] = f2bf(wv1.y);
    Ws[(n4 * 4 + 2) * APAD + k] = f2bf(wv1.z);
    Ws[(n4 * 4 + 3) * APAD + k] = f2bf(wv1.w);
  }
  // stage As tile from comb (coalesced bf16x8)
  #pragma unroll
  for (int it = 0; it < 4; ++it) {
    int idx = it * 256 + tid;           // 1024 uint4 = 128 rows x 8
    int row = idx >> 3, ch = idx & 7;
    int g = rowBase * 8 + idx;
    uint4 u = (g < N_NODES * 8) ? ((const uint4*)comb)[g] : make_uint4(0, 0, 0, 0);
    *(uint4*)&As[row * APAD + ch * 8] = u;
  }
  __syncthreads();

  f32x4 acc[2][8];
  #pragma unroll
  for (int mt = 0; mt < 2; ++mt) {
    #pragma unroll
    for (int nt = 0; nt < 8; ++nt) acc[mt][nt] = (f32x4)0.0f;
  }
  const int rw = wv * 32;
  #pragma unroll
  for (int kb = 0; kb < 2; ++kb) {
    short8 a0 = *(short8*)&As[(rw + ln) * APAD + kb * 32 + quad * 8];
    short8 a1 = *(short8*)&As[(rw + 16 + ln) * APAD + kb * 32 + quad * 8];
    #pragma unroll
    for (int nt = 0; nt < 8; ++nt) {
      short8 b = *(short8*)&Ws[(nt * 16 + ln) * APAD + kb * 32 + quad * 8];
      acc[0][nt] = __builtin_amdgcn_mfma_f32_16x16x32_bf16(a0, b, acc[0][nt], 0, 0, 0);
      acc[1][nt] = __builtin_amdgcn_mfma_f32_16x16x32_bf16(a1, b, acc[1][nt], 0, 0, 0);
    }
  }

  float bias[8], s[8], q[8];
  #pragma unroll
  for (int nt = 0; nt < 8; ++nt) { bias[nt] = b1[nt * 16 + ln]; s[nt] = 0.f; q[nt] = 0.f; }
  #pragma unroll
  for (int mt = 0; mt < 2; ++mt) {
    #pragma unroll
    for (int i = 0; i < 4; ++i) {
      int gRow = rowBase + rw + mt * 16 + quad * 4 + i;
      if (gRow < N_NODES) {
        #pragma unroll
        for (int nt = 0; nt < 8; ++nt) {
          float v = acc[mt][nt][i] + bias[nt];
          h1[gRow * 128 + nt * 16 + ln] = f2bf(v);
          s[nt] += v; q[nt] += v * v;
        }
      }
    }
  }
  #pragma unroll
  for (int nt = 0; nt < 8; ++nt) {
    s[nt] += __shfl_xor(s[nt], 16); s[nt] += __shfl_xor(s[nt], 32);
    q[nt] += __shfl_xor(q[nt], 16); q[nt] += __shfl_xor(q[nt], 32);
  }
  if (lane < 16) {
    #pragma unroll
    for (int nt = 0; nt < 8; ++nt) red[wv][nt * 16 + ln] = s[nt];
  }
  __syncthreads();
  if (tid < 128) DEV_ATOMIC_ADD(&stats[S1SUM + tid],
                                red[0][tid] + red[1][tid] + red[2][tid] + red[3][tid]);
  __syncthreads();
  if (lane < 16) {
    #pragma unroll
    for (int nt = 0; nt < 8; ++nt) red[wv][nt * 16 + ln] = q[nt];
  }
  __syncthreads();
  if (tid < 128) DEV_ATOMIC_ADD(&stats[S1SQ + tid],
                                red[0][tid] + red[1][tid] + red[2][tid] + red[3][tid]);
}

// ---- gemm2: h2(bf16) = relu(bn1(h1)) @ W2 + b2 (bf16 MFMA), fused BN2 raw stats ----
#define WPAD 136
__global__ __launch_bounds__(256) void k_gemm2(const unsigned short* __restrict__ h1,
                                               const float* __restrict__ W2,
                                               const float* __restrict__ b2,
                                               const float* __restrict__ g1,
                                               const float* __restrict__ be1,
                                               unsigned short* __restrict__ h2,
                                               float* __restrict__ stats) {
  __shared__ unsigned short As[128 * APAD];
  __shared__ unsigned short Ws[64 * WPAD];
  __shared__ float red[4][64];
  __shared__ float scL[128], shL[128];
  const int tid = threadIdx.x;
  const int wv = tid >> 6, lane = tid & 63;
  const int quad = lane >> 4, ln = lane & 15;
  const int rowBase = blockIdx.x * 128;

  if (tid < 128) {
    float mean = stats[S1SUM + tid] * (1.0f / N_NODES);
    float var = stats[S1SQ + tid] * (1.0f / N_NODES) - mean * mean;
    var = fmaxf(var, 0.0f);
    float sc = g1[tid] * rsqrtf(var + BN_EPS);
    scL[tid] = sc;
    shL[tid] = be1[tid] - mean * sc;
  }
  #pragma unroll
  for (int it = 0; it < 8; ++it) {
    int idx = it * 256 + tid;
    int k = idx >> 4, n4 = idx & 15;
    float4 wv2 = *(const float4*)(W2 + k * 64 + n4 * 4);
    Ws[(n4 * 4 + 0) * WPAD + k] = f2bf(wv2.x);
    Ws[(n4 * 4 + 1) * WPAD + k] = f2bf(wv2.y);
    Ws[(n4 * 4 + 2) * WPAD + k] = f2bf(wv2.z);
    Ws[(n4 * 4 + 3) * WPAD + k] = f2bf(wv2.w);
  }

  f32x4 acc[2][4];
  #pragma unroll
  for (int mt = 0; mt < 2; ++mt) {
    #pragma unroll
    for (int nt = 0; nt < 4; ++nt) acc[mt][nt] = (f32x4)0.0f;
  }
  const int rw = wv * 32;

  for (int kc = 0; kc < 2; ++kc) {
    __syncthreads();
    #pragma unroll
    for (int it = 0; it < 4; ++it) {
      int idx = it * 256 + tid;
      int row = idx >> 3, ch = idx & 7;
      int gRow = rowBase + row;
      uint4 u = (gRow < N_NODES) ? *(const uint4*)(h1 + gRow * 128 + kc * 64 + ch * 8)
                                 : make_uint4(0, 0, 0, 0);
      int kb = kc * 64 + ch * 8;
      float f0 = fmaxf(bflo(u.x) * scL[kb + 0] + shL[kb + 0], 0.f);
      float f1 = fmaxf(bfhi(u.x) * scL[kb + 1] + shL[kb + 1], 0.f);
      float f2 = fmaxf(bflo(u.y) * scL[kb + 2] + shL[kb + 2], 0.f);
      float f3 = fmaxf(bfhi(u.y) * scL[kb + 3] + shL[kb + 3], 0.f);
      float f4 = fmaxf(bflo(u.z) * scL[kb + 4] + shL[kb + 4], 0.f);
      float f5 = fmaxf(bfhi(u.z) * scL[kb + 5] + shL[kb + 5], 0.f);
      float f6 = fmaxf(bflo(u.w) * scL[kb + 6] + shL[kb + 6], 0.f);
      float f7 = fmaxf(bfhi(u.w) * scL[kb + 7] + shL[kb + 7], 0.f);
      uint4 o;
      o.x = (unsigned)f2bf(f0) | ((unsigned)f2bf(f1) << 16);
      o.y = (unsigned)f2bf(f2) | ((unsigned)f2bf(f3) << 16);
      o.z = (unsigned)f2bf(f4) | ((unsigned)f2bf(f5) << 16);
      o.w = (unsigned)f2bf(f6) | ((unsigned)f2bf(f7) << 16);
      *(uint4*)&As[row * APAD + ch * 8] = o;
    }
    __syncthreads();
    #pragma unroll
    for (int kb = 0; kb < 2; ++kb) {
      short8 a0 = *(short8*)&As[(rw + ln) * APAD + kb * 32 + quad * 8];
      short8 a1 = *(short8*)&As[(rw + 16 + ln) * APAD + kb * 32 + quad * 8];
      #pragma unroll
      for (int nt = 0; nt < 4; ++nt) {
        short8 b = *(short8*)&Ws[(nt * 16 + ln) * WPAD + kc * 64 + kb * 32 + quad * 8];
        acc[0][nt] = __builtin_amdgcn_mfma_f32_16x16x32_bf16(a0, b, acc[0][nt], 0, 0, 0);
        acc[1][nt] = __builtin_amdgcn_mfma_f32_16x16x32_bf16(a1, b, acc[1][nt], 0, 0, 0);
      }
    }
  }

  float bias[4], s[4], q[4];
  #pragma unroll
  for (int nt = 0; nt < 4; ++nt) { bias[nt] = b2[nt * 16 + ln]; s[nt] = 0.f; q[nt] = 0.f; }
  #pragma unroll
  for (int mt = 0; mt < 2; ++mt) {
    #pragma unroll
    for (int i = 0; i < 4; ++i) {
      int gRow = rowBase + rw + mt * 16 + quad * 4 + i;
      if (gRow < N_NODES) {
        #pragma unroll
        for (int nt = 0; nt < 4; ++nt) {
          float v = acc[mt][nt][i] + bias[nt];
          h2[gRow * 64 + nt * 16 + ln] = f2bf(v);
          s[nt] += v; q[nt] += v * v;
        }
      }
    }
  }
  #pragma unroll
  for (int nt = 0; nt < 4; ++nt) {
    s[nt] += __shfl_xor(s[nt], 16); s[nt] += __shfl_xor(s[nt], 32);
    q[nt] += __shfl_xor(q[nt], 16); q[nt] += __shfl_xor(q[nt], 32);
  }
  if (lane < 16) {
    #pragma unroll
    for (int nt = 0; nt < 4; ++nt) red[wv][nt * 16 + ln] = s[nt];
  }
  __syncthreads();
  if (tid < 64) DEV_ATOMIC_ADD(&stats[S2SUM + tid],
                               red[0][tid] + red[1][tid] + red[2][tid] + red[3][tid]);
  __syncthreads();
  if (lane < 16) {
    #pragma unroll
    for (int nt = 0; nt < 4; ++nt) red[wv][nt * 16 + ln] = q[nt];
  }
  __syncthreads();
  if (tid < 64) DEV_ATOMIC_ADD(&stats[S2SQ + tid],
                               red[0][tid] + red[1][tid] + red[2][tid] + red[3][tid]);
}

// ---- out = bn2(h2 bf16), per-block BN2 finalize ----
__global__ __launch_bounds__(256) void k_out(const unsigned short* __restrict__ h2,
                                             const float* __restrict__ stats,
                                             const float* __restrict__ g2,
                                             const float* __restrict__ be2,
                                             float* __restrict__ out) {
  __shared__ float scL[64], shL[64];
  const int tid = threadIdx.x;
  if (tid < 64) {
    float mean = stats[S2SUM + tid] * (1.0f / N_NODES);
    float var = stats[S2SQ + tid] * (1.0f / N_NODES) - mean * mean;
    var = fmaxf(var, 0.0f);
    float sc = g2[tid] * rsqrtf(var + BN_EPS);
    scL[tid] = sc;
    shL[tid] = be2[tid] - mean * sc;
  }
  __syncthreads();
  int i = blockIdx.x * 256 + tid;
  if (i < N_NODES * OUT_DIM / 4) {
    int c = i & 15;
    uint2 u = *(const uint2*)(h2 + i * 4);
    float4 v = {bflo(u.x), bfhi(u.x), bflo(u.y), bfhi(u.y)};
    float4 sc = ((const float4*)scL)[c];
    float4 sh = ((const float4*)shL)[c];
    v.x = v.x * sc.x + sh.x;
    v.y = v.y * sc.y + sh.y;
    v.z = v.z * sc.z + sh.z;
    v.w = v.w * sc.w + sh.w;
    ((float4*)out)[i] = v;
  }
}

extern "C" void kernel_launch(void* const* d_in, const int* in_sizes, int n_in,
                              void* d_out, int out_size, void* d_ws, size_t ws_size,
                              hipStream_t stream) {
  const float* x   = (const float*)d_in[0];
  const int*   ei  = (const int*)d_in[1];
  const float* eps = (const float*)d_in[2];
  const float* W1  = (const float*)d_in[3];
  const float* b1  = (const float*)d_in[4];
  const float* g1  = (const float*)d_in[5];
  const float* be1 = (const float*)d_in[6];
  const float* W2  = (const float*)d_in[7];
  const float* b2  = (const float*)d_in[8];
  const float* g2  = (const float*)d_in[9];
  const float* be2 = (const float*)d_in[10];

  float* ws = (float*)d_ws;
  unsigned short* xb     = (unsigned short*)(ws + OFF_XB);
  int*            srcl   = (int*)(ws + OFF_SRCL);
  int2*           binned = (int2*)(ws + OFF_BINNED);
  unsigned short* comb   = (unsigned short*)(ws + OFF_COMB);
  unsigned short* h1     = (unsigned short*)(ws + OFF_H1);
  unsigned short* h2     = (unsigned short*)(ws + OFF_H2);
  int*            cnt    = (int*)(ws + OFF_CNT);
  float*          stats  = ws + OFF_STATS;
  int*            bcnt   = (int*)(stats + 768);   // 256 ints
  float*          out    = (float*)d_out;

  // memset covers stats(768) + bcnt(256)
  hipMemsetAsync(stats, 0, 1024 * sizeof(float), stream);

  const int edgeGrid = (N_EDGES + 2047) / 2048;            // 782
  const int gemmGrid = (N_NODES + 127) / 128;              // 782
  const int gatherGrid = (N_NODES * 8 + 255) / 256;        // 3125
  k_bsplit<<<edgeGrid, 256, 0, stream>>>(x, xb, ei, bcnt, binned);
  k_bfill<<<NBIN_BLOCKS, 512, 0, stream>>>(bcnt, binned, cnt, srcl);
  k_gather<<<gatherGrid, 256, 0, stream>>>(xb, eps, cnt, srcl, comb);
  k_gemm1<<<gemmGrid, 256, 0, stream>>>(comb, W1, b1, h1, stats);
  k_gemm2<<<gemmGrid, 256, 0, stream>>>(h1, W2, b2, g1, be1, h2, stats);
  k_out<<<(N_NODES * OUT_DIM / 4 + 255) / 256, 256, 0, stream>>>(h2, stats, g2, be2, out);
}